// Round 1
// baseline (579.849 us; speedup 1.0000x reference)
//
#include <hip/hip_runtime.h>
#include <stdint.h>

// Problem constants
#define NB 64      // tokens per (b,t) group
#define DD 256     // input dim
#define HH 512     // hidden dim
#define NGROUP 2048 // B*T

// LDS strides (f16 elems), padded +8 -> row stride = 4 banks (conflict-free b128)
#define LDX 264    // [64][264] x / A / g buffers
#define LDT 72     // [256][72] transposed x ; [64][72] P
#define LDH 520    // [64][520] h buffer
#define LDSC 68    // f32 score scratch stride

typedef __attribute__((ext_vector_type(8))) _Float16 half8;
typedef __attribute__((ext_vector_type(4))) float f32x4;

__device__ __forceinline__ half8 ld8(const _Float16* p) {
    return *reinterpret_cast<const half8*>(p);
}

// ---------------- precompute kernels (weights -> f16, fused & transposed) ----

// G[d][e] = scale * sum_h Wq[d,h] * Wk[e,h]      (G row-major [256][256])
__global__ void prep_G_kernel(const float* __restrict__ Wq, const float* __restrict__ Wk,
                              _Float16* __restrict__ G, float scale) {
    const int d = blockIdx.x;   // 0..255
    const int e = threadIdx.x;  // 0..255
    const float4* qa = reinterpret_cast<const float4*>(Wq + d * HH);
    const float4* ka = reinterpret_cast<const float4*>(Wk + e * HH);
    float s = 0.f;
    #pragma unroll 8
    for (int j = 0; j < HH / 4; ++j) {
        float4 a = qa[j], b = ka[j];
        s += a.x * b.x + a.y * b.y + a.z * b.z + a.w * b.w;
    }
    G[d * DD + e] = (_Float16)(s * scale);
}

// UT[o][d] = sum_j Wv[d,j] * W1p[j,o]            (UT row-major [512][256])
__global__ void prep_U_kernel(const float* __restrict__ Wv, const float* __restrict__ W1p,
                              _Float16* __restrict__ UT) {
    const int o = blockIdx.x;   // 0..511
    const int d = threadIdx.x;  // 0..255
    const float4* va = reinterpret_cast<const float4*>(Wv + d * HH);
    float s = 0.f;
    #pragma unroll 4
    for (int j4 = 0; j4 < HH / 4; ++j4) {
        float4 a = va[j4];
        const int j = j4 * 4;
        s += a.x * W1p[(j + 0) * HH + o];
        s += a.y * W1p[(j + 1) * HH + o];
        s += a.z * W1p[(j + 2) * HH + o];
        s += a.w * W1p[(j + 3) * HH + o];
    }
    UT[o * DD + d] = (_Float16)s;
}

// W2T[k][h] = W2[h][k]                            (f16, [512][512])
__global__ void prep_W2T_kernel(const float* __restrict__ W2, _Float16* __restrict__ W2T) {
    __shared__ float tile[32][33];
    const int bk = blockIdx.x * 32;
    const int bh = blockIdx.y * 32;
    const int tx = threadIdx.x & 31, ty = threadIdx.x >> 5;  // 32x8
    #pragma unroll
    for (int i = 0; i < 32; i += 8)
        tile[ty + i][tx] = W2[(bh + ty + i) * HH + bk + tx];
    __syncthreads();
    #pragma unroll
    for (int i = 0; i < 32; i += 8)
        W2T[(bk + ty + i) * HH + bh + tx] = (_Float16)tile[tx][ty + i];
}

// ---------------- main fused kernel helpers ----------------

// C[64 x 256] = A[64 x K] * B, B given "col-major-for-B": B[col][k] contiguous.
// 8 waves, 32 cols each; Dst f16 [64][LDD].
template <int K, int LDA, int LDB, int LDD>
__device__ __forceinline__ void gemm_64_tile(const _Float16* A, const _Float16* B,
                                             _Float16* Dst, int lane, int w) {
    const int c = lane & 15, kg = lane >> 4;
    const int colbase = w * 32;
    const f32x4 z = {0.f, 0.f, 0.f, 0.f};
    f32x4 acc[4][2];
    #pragma unroll
    for (int i = 0; i < 4; ++i) { acc[i][0] = z; acc[i][1] = z; }
    for (int k0 = 0; k0 < K; k0 += 32) {
        const int ko = k0 + kg * 8;
        half8 a[4], b[2];
        #pragma unroll
        for (int i = 0; i < 4; ++i) a[i] = ld8(A + (16 * i + c) * LDA + ko);
        #pragma unroll
        for (int j = 0; j < 2; ++j) b[j] = ld8(B + (colbase + 16 * j + c) * LDB + ko);
        #pragma unroll
        for (int i = 0; i < 4; ++i) {
            acc[i][0] = __builtin_amdgcn_mfma_f32_16x16x32_f16(a[i], b[0], acc[i][0], 0, 0, 0);
            acc[i][1] = __builtin_amdgcn_mfma_f32_16x16x32_f16(a[i], b[1], acc[i][1], 0, 0, 0);
        }
    }
    #pragma unroll
    for (int i = 0; i < 4; ++i)
        #pragma unroll
        for (int j = 0; j < 2; ++j) {
            const int col = colbase + 16 * j + c;
            const int r0 = 16 * i + kg * 4;
            #pragma unroll
            for (int r = 0; r < 4; ++r)
                Dst[(r0 + r) * LDD + col] = (_Float16)acc[i][j][r];
        }
}

// S[64 x 64] = A[64 x 256] * Bl (Bl row-major [64][LDX], contraction over its cols)
__device__ __forceinline__ void gemm_s(const _Float16* A, const _Float16* Bl, float* S,
                                       int lane, int w) {
    const int c = lane & 15, kg = lane >> 4;
    const int rowbase = (w >> 1) * 16;
    const int colbase = (w & 1) * 32;
    const f32x4 z = {0.f, 0.f, 0.f, 0.f};
    f32x4 acc0 = z, acc1 = z;
    for (int k0 = 0; k0 < DD; k0 += 32) {
        const int ko = k0 + kg * 8;
        half8 a  = ld8(A  + (rowbase + c) * LDX + ko);
        half8 u0 = ld8(Bl + (colbase + c) * LDX + ko);
        half8 u1 = ld8(Bl + (colbase + 16 + c) * LDX + ko);
        acc0 = __builtin_amdgcn_mfma_f32_16x16x32_f16(a, u0, acc0, 0, 0, 0);
        acc1 = __builtin_amdgcn_mfma_f32_16x16x32_f16(a, u1, acc1, 0, 0, 0);
    }
    const int r0 = rowbase + kg * 4;
    #pragma unroll
    for (int r = 0; r < 4; ++r) {
        S[(r0 + r) * LDSC + colbase + c]      = acc0[r];
        S[(r0 + r) * LDSC + colbase + 16 + c] = acc1[r];
    }
}

// row-softmax of S[64][LDSC] f32 -> P[64][LDT] f16. 8 threads per row.
__device__ __forceinline__ void softmax64(const float* S, _Float16* P, int tid) {
    const int row = tid >> 3, seg = tid & 7;
    const float* sp = S + row * LDSC + seg * 8;
    float v[8];
    #pragma unroll
    for (int i = 0; i < 8; ++i) v[i] = sp[i];
    float m = v[0];
    #pragma unroll
    for (int i = 1; i < 8; ++i) m = fmaxf(m, v[i]);
    #pragma unroll
    for (int d = 1; d < 8; d <<= 1) m = fmaxf(m, __shfl_xor(m, d));
    float s = 0.f;
    #pragma unroll
    for (int i = 0; i < 8; ++i) { v[i] = __expf(v[i] - m); s += v[i]; }
    #pragma unroll
    for (int d = 1; d < 8; d <<= 1) s += __shfl_xor(s, d);
    const float inv = 1.f / s;
    half8 ph;
    #pragma unroll
    for (int i = 0; i < 8; ++i) ph[i] = (_Float16)(v[i] * inv);
    *reinterpret_cast<half8*>(P + row * LDT + seg * 8) = ph;
}

// ---------------- main fused kernel ----------------
// LDS map (bytes):
//  X1  @      0 (33792)  x1 f16 [64][264]      -> later g1
//  X2  @  33792 (33792)  x2 f16                -> later g2
//  SC  @  67584 (36864)  A2 | S2 scratch | X1T | h(part)
//  SD  @ 104448 (36864)  S1 scratch | A1 | X2T | h(part)
//  P1  @ 141312 (9216), P2 @ 150528 (9216)     total 159744 <= 160 KiB
__global__ __launch_bounds__(512, 2)
void fused_kernel(const float* __restrict__ x1g, const float* __restrict__ x2g,
                  const _Float16* __restrict__ G1, const _Float16* __restrict__ G2,
                  const _Float16* __restrict__ U1T, const _Float16* __restrict__ U2T,
                  const _Float16* __restrict__ W2T,
                  const float* __restrict__ b1, const float* __restrict__ b2,
                  float* __restrict__ out) {
    __shared__ char lds[159744];
    _Float16* const X1 = reinterpret_cast<_Float16*>(lds + 0);
    _Float16* const X2 = reinterpret_cast<_Float16*>(lds + 33792);
    _Float16* const SC = reinterpret_cast<_Float16*>(lds + 67584);
    _Float16* const SD = reinterpret_cast<_Float16*>(lds + 104448);
    _Float16* const P1 = reinterpret_cast<_Float16*>(lds + 141312);
    _Float16* const P2 = reinterpret_cast<_Float16*>(lds + 150528);
    float* const SCf = reinterpret_cast<float*>(SC);
    float* const SDf = reinterpret_cast<float*>(SD);

    const int tid = threadIdx.x;
    const int lane = tid & 63;
    const int w = tid >> 6;
    const int c = lane & 15;
    const int kg = lane >> 4;
    const size_t g = blockIdx.x;

    // ---- Phase 0: stage x1, x2 -> f16 LDS ----
    {
        const float4* s1 = reinterpret_cast<const float4*>(x1g) + g * (NB * DD / 4);
        const float4* s2 = reinterpret_cast<const float4*>(x2g) + g * (NB * DD / 4);
        for (int idx = tid; idx < NB * DD / 4; idx += 512) {
            const int row = idx >> 6;
            const int c4 = (idx & 63) * 4;
            float4 a = s1[idx];
            float4 b = s2[idx];
            union { _Float16 h[4]; uint32_t u[2]; } pa, pb;
            pa.h[0] = (_Float16)a.x; pa.h[1] = (_Float16)a.y;
            pa.h[2] = (_Float16)a.z; pa.h[3] = (_Float16)a.w;
            pb.h[0] = (_Float16)b.x; pb.h[1] = (_Float16)b.y;
            pb.h[2] = (_Float16)b.z; pb.h[3] = (_Float16)b.w;
            uint32_t* d1 = reinterpret_cast<uint32_t*>(X1 + row * LDX + c4);
            uint32_t* d2 = reinterpret_cast<uint32_t*>(X2 + row * LDX + c4);
            d1[0] = pa.u[0]; d1[1] = pa.u[1];
            d2[0] = pb.u[0]; d2[1] = pb.u[1];
        }
    }
    __syncthreads();

    // ---- Phase 1: A2[m,d] = sum_e x2[m,e] * G1[d,e]  -> SC ----
    gemm_64_tile<DD, LDX, DD, LDX>(X2, G1, SC, lane, w);
    __syncthreads();

    // ---- Phase 2: S1[n,m] = sum_d x1[n,d] * A2[m,d]; softmax -> P1 ----
    gemm_s(X1, SC, SDf, lane, w);
    __syncthreads();
    softmax64(SDf, P1, tid);
    __syncthreads();

    // ---- Phase 3: A1[m,d] = sum_e x1[m,e] * G2[d,e]  -> SD ----
    gemm_64_tile<DD, LDX, DD, LDX>(X1, G2, SD, lane, w);
    __syncthreads();

    // ---- Phase 4: S2[n,m] = sum_d x2[n,d] * A1[m,d]; softmax -> P2 ----
    gemm_s(X2, SD, SCf, lane, w);
    __syncthreads();
    softmax64(SCf, P2, tid);
    __syncthreads();

    // ---- Phase 5: X1T = X1^T -> SC, X2T = X2^T -> SD ([256][72]) ----
    {
        _Float16* const X1T = SC;
        _Float16* const X2T = SD;
        for (int idx = tid; idx < NB * DD / 8; idx += 512) {
            const int row = idx & 63;
            const int c0 = (idx >> 6) * 8;
            half8 va = ld8(X1 + row * LDX + c0);
            half8 vb = ld8(X2 + row * LDX + c0);
            #pragma unroll
            for (int j = 0; j < 8; ++j) {
                X1T[(c0 + j) * LDT + row] = va[j];
                X2T[(c0 + j) * LDT + row] = vb[j];
            }
        }
    }
    __syncthreads();

    // ---- Phase 6: g1 = P1 @ x1 -> X1 slot ; g2 = P2 @ x2 -> X2 slot ----
    gemm_64_tile<NB, LDT, LDT, LDX>(P1, SC, X1, lane, w);
    gemm_64_tile<NB, LDT, LDT, LDX>(P2, SD, X2, lane, w);
    __syncthreads();

    // ---- Phase 7: h = relu(g1@U1 + g2@U2 + b1) -> Hbuf [64][520] over SC..SD ----
    _Float16* const Hbuf = SC;
    {
        const int colbase = w * 64;
        const f32x4 z = {0.f, 0.f, 0.f, 0.f};
        f32x4 acc[4][4];
        #pragma unroll
        for (int i = 0; i < 4; ++i)
            #pragma unroll
            for (int j = 0; j < 4; ++j) acc[i][j] = z;
        for (int k0 = 0; k0 < DD; k0 += 32) {
            const int ko = k0 + kg * 8;
            half8 a[4], b[4];
            #pragma unroll
            for (int i = 0; i < 4; ++i) a[i] = ld8(X1 + (16 * i + c) * LDX + ko);
            #pragma unroll
            for (int j = 0; j < 4; ++j) b[j] = ld8(U1T + (colbase + 16 * j + c) * DD + ko);
            #pragma unroll
            for (int i = 0; i < 4; ++i)
                #pragma unroll
                for (int j = 0; j < 4; ++j)
                    acc[i][j] = __builtin_amdgcn_mfma_f32_16x16x32_f16(a[i], b[j], acc[i][j], 0, 0, 0);
        }
        for (int k0 = 0; k0 < DD; k0 += 32) {
            const int ko = k0 + kg * 8;
            half8 a[4], b[4];
            #pragma unroll
            for (int i = 0; i < 4; ++i) a[i] = ld8(X2 + (16 * i + c) * LDX + ko);
            #pragma unroll
            for (int j = 0; j < 4; ++j) b[j] = ld8(U2T + (colbase + 16 * j + c) * DD + ko);
            #pragma unroll
            for (int i = 0; i < 4; ++i)
                #pragma unroll
                for (int j = 0; j < 4; ++j)
                    acc[i][j] = __builtin_amdgcn_mfma_f32_16x16x32_f16(a[i], b[j], acc[i][j], 0, 0, 0);
        }
        #pragma unroll
        for (int j = 0; j < 4; ++j) {
            const int col = colbase + 16 * j + c;
            const float bb = b1[col];
            #pragma unroll
            for (int i = 0; i < 4; ++i) {
                const int r0 = 16 * i + kg * 4;
                #pragma unroll
                for (int r = 0; r < 4; ++r) {
                    float hv = fmaxf(acc[i][j][r] + bb, 0.f);
                    Hbuf[(r0 + r) * LDH + col] = (_Float16)hv;
                }
            }
        }
    }
    __syncthreads();

    // ---- Phase 8: out = h @ W2 + b2 (f32 to global) ----
    {
        const int colbase = w * 64;
        const f32x4 z = {0.f, 0.f, 0.f, 0.f};
        f32x4 acc[4][4];
        #pragma unroll
        for (int i = 0; i < 4; ++i)
            #pragma unroll
            for (int j = 0; j < 4; ++j) acc[i][j] = z;
        for (int k0 = 0; k0 < HH; k0 += 32) {
            const int ko = k0 + kg * 8;
            half8 a[4], b[4];
            #pragma unroll
            for (int i = 0; i < 4; ++i) a[i] = ld8(Hbuf + (16 * i + c) * LDH + ko);
            #pragma unroll
            for (int j = 0; j < 4; ++j) b[j] = ld8(W2T + (colbase + 16 * j + c) * HH + ko);
            #pragma unroll
            for (int i = 0; i < 4; ++i)
                #pragma unroll
                for (int j = 0; j < 4; ++j)
                    acc[i][j] = __builtin_amdgcn_mfma_f32_16x16x32_f16(a[i], b[j], acc[i][j], 0, 0, 0);
        }
        float* og = out + g * (size_t)(NB * HH);
        #pragma unroll
        for (int j = 0; j < 4; ++j) {
            const int col = colbase + 16 * j + c;
            const float bb = b2[col];
            #pragma unroll
            for (int i = 0; i < 4; ++i) {
                const int r0 = 16 * i + kg * 4;
                #pragma unroll
                for (int r = 0; r < 4; ++r)
                    og[(size_t)(r0 + r) * HH + col] = acc[i][j][r] + bb;
            }
        }
    }
}

// ---------------- launch ----------------

extern "C" void kernel_launch(void* const* d_in, const int* in_sizes, int n_in,
                              void* d_out, int out_size, void* d_ws, size_t ws_size,
                              hipStream_t stream) {
    (void)in_sizes; (void)n_in; (void)out_size; (void)ws_size;
    const float* x1  = (const float*)d_in[0];
    const float* x2  = (const float*)d_in[1];
    const float* Wq1 = (const float*)d_in[2];
    const float* Wk1 = (const float*)d_in[3];
    const float* Wv1 = (const float*)d_in[4];
    const float* Wq2 = (const float*)d_in[5];
    const float* Wk2 = (const float*)d_in[6];
    const float* Wv2 = (const float*)d_in[7];
    const float* W1  = (const float*)d_in[8];
    const float* b1  = (const float*)d_in[9];
    const float* W2  = (const float*)d_in[10];
    const float* b2  = (const float*)d_in[11];
    float* out = (float*)d_out;

    // workspace layout (f16), total 1,310,720 bytes
    char* ws = (char*)d_ws;
    _Float16* G1  = (_Float16*)(ws + 0);        // 256*256*2 = 131072
    _Float16* G2  = (_Float16*)(ws + 131072);   // 131072
    _Float16* U1T = (_Float16*)(ws + 262144);   // 512*256*2 = 262144
    _Float16* U2T = (_Float16*)(ws + 524288);   // 262144
    _Float16* W2T = (_Float16*)(ws + 786432);   // 512*512*2 = 524288

    const float scale = 0.0625f;  // D^-0.5 = 1/16

    prep_G_kernel<<<DD, DD, 0, stream>>>(Wq1, Wk2, G1, scale);
    prep_G_kernel<<<DD, DD, 0, stream>>>(Wq2, Wk1, G2, scale);
    prep_U_kernel<<<HH, DD, 0, stream>>>(Wv1, W1, U1T);
    prep_U_kernel<<<HH, DD, 0, stream>>>(Wv2, W1 + HH * HH, U2T);
    prep_W2T_kernel<<<dim3(16, 16), 256, 0, stream>>>(W2, W2T);

    fused_kernel<<<NGROUP, 512, 0, stream>>>(x1, x2, G1, G2, U1T, U2T, W2T, b1, b2, out);
}